// Round 1
// baseline (53.625 us; speedup 1.0000x reference)
//
#include <hip/hip_runtime.h>
#include <hip/hip_bf16.h>

#define H_DIM 3072
#define W_DIM 3072

__global__ __launch_bounds__(256) void rotation_kernel(
    const float* __restrict__ img,     // (H, W, 3) f32
    const float* __restrict__ fv,      // (1,) f32
    float* __restrict__ out)           // (H, W, 3) f32
{
    const int c = blockIdx.x * blockDim.x + threadIdx.x;
    const int r = blockIdx.y;
    if (c >= W_DIM) return;

    // theta = deg2rad(frame_value[0] * 20)
    const float theta = fv[0] * 20.0f * (3.14159265358979323846f / 180.0f);
    float st, ct;
    __sincosf(theta, &st, &ct);
    // __sincosf is fast-math; use precise versions to stay close to JAX
    ct = cosf(theta);
    st = sinf(theta);

    const float o_r = (float)H_DIM / 2.0f + 0.5f;   // 1536.5
    const float o_c = (float)W_DIM / 2.0f + 0.5f;

    const float dr = (float)r - o_r;
    const float dc = (float)c - o_c;

    float src_r = ct * dr - st * dc + o_r;
    float src_c = st * dr + ct * dc + o_c;

    // fill_mode='nearest' -> clamp to valid range
    src_r = fminf(fmaxf(src_r, 0.0f), (float)(H_DIM - 1));
    src_c = fminf(fmaxf(src_c, 0.0f), (float)(W_DIM - 1));

    const float r0f = floorf(src_r);
    const float c0f = floorf(src_c);
    const float wr = src_r - r0f;
    const float wc = src_c - c0f;

    const int r0 = (int)r0f;
    const int c0 = (int)c0f;
    const int r1 = min(r0 + 1, H_DIM - 1);
    const int c1 = min(c0 + 1, W_DIM - 1);

    const float w00 = (1.0f - wr) * (1.0f - wc);
    const float w01 = (1.0f - wr) * wc;
    const float w10 = wr * (1.0f - wc);
    const float w11 = wr * wc;

    const float* p00 = img + ((size_t)r0 * W_DIM + c0) * 3;
    const float* p01 = img + ((size_t)r0 * W_DIM + c1) * 3;
    const float* p10 = img + ((size_t)r1 * W_DIM + c0) * 3;
    const float* p11 = img + ((size_t)r1 * W_DIM + c1) * 3;

    float* o = out + ((size_t)r * W_DIM + c) * 3;
    #pragma unroll
    for (int ch = 0; ch < 3; ++ch) {
        o[ch] = w00 * p00[ch] + w01 * p01[ch] + w10 * p10[ch] + w11 * p11[ch];
    }
}

extern "C" void kernel_launch(void* const* d_in, const int* in_sizes, int n_in,
                              void* d_out, int out_size, void* d_ws, size_t ws_size,
                              hipStream_t stream) {
    const float* img = (const float*)d_in[0];
    const float* fv  = (const float*)d_in[1];
    float* out = (float*)d_out;

    dim3 block(256, 1, 1);
    dim3 grid(W_DIM / 256, H_DIM, 1);
    rotation_kernel<<<grid, block, 0, stream>>>(img, fv, out);
}

// Round 2
// 52.292 us; speedup vs baseline: 1.0255x; 1.0255x over previous
//
#include <hip/hip_runtime.h>
#include <hip/hip_bf16.h>

#define H_DIM 3072
#define W_DIM 3072

// 4-byte-aligned vector types: hardware (gfx950 global_load) supports
// unaligned vector loads; aligned(4) keeps the C++ side legal since tap
// base addresses are only 4B-aligned ((r*W+c)*12 bytes).
typedef float f32x4 __attribute__((ext_vector_type(4)));
typedef float f32x2 __attribute__((ext_vector_type(2)));
typedef f32x4 __attribute__((aligned(4))) f32x4u;
typedef f32x2 __attribute__((aligned(4))) f32x2u;

__global__ __launch_bounds__(256) void rotation_kernel(
    const float* __restrict__ img,     // (H, W, 3) f32
    const float* __restrict__ fv,      // (1,) f32
    float* __restrict__ out)           // (H, W, 3) f32
{
    // 128x8 output tile per block; each thread does 4 consecutive pixels.
    const int c_base = (blockIdx.x * 32 + threadIdx.x) * 4;
    const int r      = blockIdx.y * 8 + threadIdx.y;

    const float theta = fv[0] * 20.0f * (3.14159265358979323846f / 180.0f);
    const float ct = cosf(theta);
    const float st = sinf(theta);

    const float o_r = (float)H_DIM / 2.0f + 0.5f;   // 1536.5
    const float o_c = (float)W_DIM / 2.0f + 0.5f;
    const float dr = (float)r - o_r;

    float res[12];

    #pragma unroll
    for (int p = 0; p < 4; ++p) {
        const int c = c_base + p;
        const float dc = (float)c - o_c;

        float src_r = ct * dr - st * dc + o_r;
        float src_c = st * dr + ct * dc + o_c;
        src_r = fminf(fmaxf(src_r, 0.0f), (float)(H_DIM - 1));
        src_c = fminf(fmaxf(src_c, 0.0f), (float)(W_DIM - 1));

        const float r0f = floorf(src_r);
        const float c0f = floorf(src_c);
        const float wr = src_r - r0f;
        const float wc = src_c - c0f;

        const int r0 = (int)r0f;
        const int c0 = (int)c0f;
        const int r1 = min(r0 + 1, H_DIM - 1);
        // Load base clamped so the 2-pixel (6-float) row segment never
        // reads past the buffer end. When c0 == W-1, wc == 0 exactly
        // (src_c clamped to W-1), so the p01 tap value is irrelevant.
        const int cb = min(c0, W_DIM - 2);
        const bool hi = (c0 > cb);   // true only when c0 == W-1

        const float* rp0 = img + ((size_t)r0 * W_DIM + cb) * 3;
        const float* rp1 = img + ((size_t)r1 * W_DIM + cb) * 3;
        const f32x4u a0 = *(const f32x4u*)rp0;
        const f32x2u b0 = *(const f32x2u*)(rp0 + 4);
        const f32x4u a1 = *(const f32x4u*)rp1;
        const f32x2u b1 = *(const f32x2u*)(rp1 + 4);
        const float q0[6] = {a0[0], a0[1], a0[2], a0[3], b0[0], b0[1]};
        const float q1[6] = {a1[0], a1[1], a1[2], a1[3], b1[0], b1[1]};

        #pragma unroll
        for (int ch = 0; ch < 3; ++ch) {
            const float t00 = hi ? q0[3 + ch] : q0[ch];
            const float t01 = q0[3 + ch];
            const float t10 = hi ? q1[3 + ch] : q1[ch];
            const float t11 = q1[3 + ch];
            const float row0 = t00 + wc * (t01 - t00);
            const float row1 = t10 + wc * (t11 - t10);
            res[p * 3 + ch] = row0 + wr * (row1 - row0);
        }
    }

    // 48 contiguous bytes per thread, 16B-aligned: 3x dwordx4 stores.
    float4* op = (float4*)(out + ((size_t)r * W_DIM + c_base) * 3);
    op[0] = make_float4(res[0], res[1], res[2],  res[3]);
    op[1] = make_float4(res[4], res[5], res[6],  res[7]);
    op[2] = make_float4(res[8], res[9], res[10], res[11]);
}

extern "C" void kernel_launch(void* const* d_in, const int* in_sizes, int n_in,
                              void* d_out, int out_size, void* d_ws, size_t ws_size,
                              hipStream_t stream) {
    const float* img = (const float*)d_in[0];
    const float* fv  = (const float*)d_in[1];
    float* out = (float*)d_out;

    dim3 block(32, 8, 1);
    dim3 grid(W_DIM / 128, H_DIM / 8, 1);
    rotation_kernel<<<grid, block, 0, stream>>>(img, fv, out);
}